// Round 1
// baseline (5973.193 us; speedup 1.0000x reference)
//
#include <hip/hip_runtime.h>
#include <math.h>

#define B_ 128
#define L_ 30
#define M_ 10
#define H_ 256
#define VN_ 32000
#define HL_ 7936        // (L+1)*H
#define NCH 500         // VN / 64 chunks for nv gemm

typedef __bf16 bf16;
typedef bf16 bf16x8 __attribute__((ext_vector_type(8)));
typedef float f32x4 __attribute__((ext_vector_type(4)));

__device__ __forceinline__ float sigf(float x) { return 1.f / (1.f + __expf(-x)); }

// ---------------------------------------------------------------- init
__global__ __launch_bounds__(256) void k_init(
    const int* sentence, const int* keywords, const int* categories,
    const int* memsz, const float* emb,
    float* key_mem, float* val_mem,
    float* histN, float* histK, float* histV,
    float* accN, float* accK, float* accV,
    float* prev_h, bf16* peh, float* out_g) {
  int b = blockIdx.x, t = threadIdx.x;   // t in [0,256) == H
  int ms = memsz[b];
  float sk = 0.f, sv = 0.f;
  for (int m = 0; m < M_; ++m) {
    int kw = keywords[b*M_ + m], cg = categories[b*M_ + m];
    float ke = (m < ms) ? emb[(size_t)kw*H_ + t] : 0.f;
    float ve = (m < ms) ? emb[(size_t)cg*H_ + t] : 0.f;
    key_mem[(b*M_ + m)*H_ + t] = ke;
    val_mem[(b*M_ + m)*H_ + t] = ve;
    sk += ke; sv += ve;
  }
  float ih = (sk + sv) / (2.f * (float)ms);
  histN[(b*L_)*H_ + t] = ih;
  histK[(b*L_)*H_ + t] = ih;
  histV[(b*L_)*H_ + t] = ih;
  prev_h[b*H_ + t] = ih;
  peh[b*512 + 256 + t] = (bf16)ih;
  int s0 = sentence[b*L_];
  peh[b*512 + t] = (bf16)emb[(size_t)s0*H_ + t];
  if (t < L_) { accN[b*L_+t] = 0.f; accK[b*L_+t] = 0.f; accV[b*L_+t] = 0.f; }
  if (t == 0) out_g[b*L_] = 0.f;
}

// ---------------------------------------------------------------- weight -> bf16
__global__ __launch_bounds__(256) void k_conv(
    const float* W_ct, const float* W_ih, const float* W_hh,
    const float* W_n, const float* W_k, const float* W_v, const float* W_nv,
    bf16* Wctb, bf16* Wihhhb, bf16* Wnkvb, bf16* Wnvb) {
  int stride = gridDim.x * blockDim.x;
  int base = blockIdx.x * blockDim.x + threadIdx.x;
  for (int i = base; i < 256*1280; i += stride) Wctb[i] = (bf16)W_ct[i];
  for (int i = base; i < 1024*512; i += stride) {
    int n = i >> 9, j = i & 511;
    Wihhhb[i] = (bf16)(j < 256 ? W_ih[n*256 + j] : W_hh[n*256 + j - 256]);
  }
  for (int i = base; i < 768*256; i += stride) {
    int r = i >> 8, k = i & 255;
    const float* src = (r < 256) ? W_n : ((r < 512) ? W_k : W_v);
    Wnkvb[i] = (bf16)src[(r & 255)*256 + k];
  }
  for (int i = base; i < VN_*H_; i += stride) Wnvb[i] = (bf16)W_nv[i];
}

// ---------------------------------------------------------------- attn (+ combine of prev step)
struct AttnP {
  const int* sentence;
  const float *prev_h, *histN, *histK, *histV;
  float *accN, *accK, *accV;
  const float *W_hn, *b_hn, *W_hk, *b_hk, *W_hv, *b_hv;
  const float *W_mk, *b_mk, *W_mv, *b_mv;
  const float *key_mem, *val_mem;
  bf16* cat5b;
  const float *pm, *ps, *hnkv, *gt_ws, *W_nv, *b_nv;
  float* loss_arr;
};

__global__ __launch_bounds__(256) void k_attn(int di, AttnP p) {
  __shared__ float s_ph[H_], s_hp[3][H_], s_w[3][32], s_qm[1024], s_wm[2][16];
  int b = blockIdx.x, t = threadIdx.x;
  int wid = t >> 6, lane = t & 63;

  // ---- combine LSE for step di-1 (wave 3 only) ----
  if (wid == 3 && di > 1) {
    int d = di - 1;
    float M = -1e30f, S = 0.f;
    for (int c = lane; c < NCH; c += 64) {
      float m = p.pm[c*B_ + b], s = p.ps[c*B_ + b];
      float M2 = fmaxf(M, m);
      S = S*__expf(M - M2) + s*__expf(m - M2);
      M = M2;
    }
    for (int o = 1; o < 64; o <<= 1) {
      float Mo = __shfl_xor(M, o), So = __shfl_xor(S, o);
      float M2 = fmaxf(M, Mo);
      S = S*__expf(M - M2) + So*__expf(Mo - M2);
      M = M2;
    }
    int tok = p.sentence[b*L_ + d];
    float zt = 0.f;
    for (int j = 0; j < 4; ++j)
      zt += p.hnkv[b*768 + lane*4 + j] * p.W_nv[(size_t)tok*H_ + lane*4 + j];
    for (int o = 1; o < 64; o <<= 1) zt += __shfl_xor(zt, o);
    if (lane == 0) {
      zt += p.b_nv[tok];
      p.loss_arr[(d-1)*B_ + b] = -(zt - M - __logf(S) + __logf(p.gt_ws[b]));
    }
  }

  // ---- load prev_h + hist slot di-1 ----
  s_ph[t]   = p.prev_h[b*H_ + t];
  s_hp[0][t] = p.histN[(b*L_ + di-1)*H_ + t];
  s_hp[1][t] = p.histK[(b*L_ + di-1)*H_ + t];
  s_hp[2][t] = p.histV[(b*L_ + di-1)*H_ + t];
  __syncthreads();

  // ---- 90 dot pairs: acc update + w logits ----
  const float* Wh0 = p.W_hn; const float* Wh1 = p.W_hk; const float* Wh2 = p.W_hv;
  const float* bh0 = p.b_hn; const float* bh1 = p.b_hk; const float* bh2 = p.b_hv;
  for (int idx = wid; idx < 3*L_; idx += 4) {
    int X = idx / L_, l = idx - X*L_;
    const float* wrow = (X==0 ? Wh0 : X==1 ? Wh1 : Wh2) + l*HL_;
    float dA = 0.f, dB = 0.f;
    for (int j = 0; j < 4; ++j) {
      int k = lane + 64*j;
      dA += s_hp[X][k] * wrow[di*H_ + k];
      dB += s_ph[k]   * wrow[k];
    }
    for (int o = 1; o < 64; o <<= 1) { dA += __shfl_xor(dA, o); dB += __shfl_xor(dB, o); }
    if (lane == 0) {
      float* accA = (X==0 ? p.accN : X==1 ? p.accK : p.accV);
      float a = accA[b*L_ + l] + dA;
      accA[b*L_ + l] = a;
      const float* bh = (X==0 ? bh0 : X==1 ? bh1 : bh2);
      s_w[X][l] = tanhf(a + dB + bh[l]);
    }
  }
  __syncthreads();

  // ---- einsum cH (only slots < di are nonzero) ----
  for (int X = 0; X < 3; ++X) {
    const float* hist = (X==0 ? p.histN : X==1 ? p.histK : p.histV) + (size_t)b*L_*H_;
    float acc = 0.f;
    for (int l = 0; l < di; ++l) acc += s_w[X][l] * hist[l*H_ + t];
    s_qm[256 + X*256 + t] = acc;
  }
  s_qm[t] = s_ph[t];
  __syncthreads();

  // ---- memory attn logits ----
  for (int idx = wid; idx < 2*M_; idx += 4) {
    int X = idx / M_, m = idx - X*M_;
    const float* wrow = (X==0 ? p.W_mk : p.W_mv) + m*1024;
    float d = 0.f;
    for (int j = 0; j < 16; ++j) { int k = lane + 64*j; d += s_qm[k]*wrow[k]; }
    for (int o = 1; o < 64; o <<= 1) d += __shfl_xor(d, o);
    if (lane == 0) s_wm[X][m] = tanhf(d + (X==0 ? p.b_mk : p.b_mv)[m]);
  }
  __syncthreads();

  // ---- cMK/cMV + write cat5 (bf16) ----
  float cmk = 0.f, cmv = 0.f;
  for (int m = 0; m < M_; ++m) {
    cmk += s_wm[0][m] * p.key_mem[(b*M_+m)*H_ + t];
    cmv += s_wm[1][m] * p.val_mem[(b*M_+m)*H_ + t];
  }
  bf16* c5 = p.cat5b + b*1280;
  c5[t]       = (bf16)s_qm[256+t];
  c5[256+t]   = (bf16)s_qm[512+t];
  c5[512+t]   = (bf16)s_qm[768+t];
  c5[768+t]   = (bf16)cmk;
  c5[1024+t]  = (bf16)cmv;
}

// ---------------------------------------------------------------- c0 + gates GEMM (branchy)
__global__ __launch_bounds__(256) void k_mm_c0g(
    const bf16* cat5b, const bf16* peh,
    const bf16* Wctb, const bf16* Wihhhb,
    const float* b_ct, const float* b_ih, const float* b_hh,
    float* c0buf, float* gates) {
  extern __shared__ char smem[];
  char* Al = smem;                 // 128 x 128 bf16, swizzled, row stride 256B
  char* Bl = smem + 32768;         // 64 x 128 bf16
  int blk = blockIdx.x, t = threadIdx.x;
  bool isC0 = blk < 4;
  int n0 = isC0 ? blk*64 : (blk-4)*64;
  int K  = isC0 ? 1280 : 512;
  const bf16* Ap = isC0 ? cat5b : peh;
  const bf16* Bp = (isC0 ? Wctb : Wihhhb) + (size_t)n0*K;
  int wid = t>>6, lane = t&63, wr = wid>>1, wc = wid&1;
  f32x4 acc[4][2] = {};
  for (int kc = 0; kc < K; kc += 128) {
    __syncthreads();
    for (int i = t; i < 128*16; i += 256) {
      int r = i >> 4, c8 = i & 15;
      int4 v = *(const int4*)(Ap + (size_t)r*K + kc + c8*8);
      *(int4*)(Al + ((r*256 + c8*16) ^ ((r&7)<<4))) = v;
    }
    for (int i = t; i < 64*16; i += 256) {
      int r = i >> 4, c8 = i & 15;
      int4 v = *(const int4*)(Bp + (size_t)r*K + kc + c8*8);
      *(int4*)(Bl + ((r*256 + c8*16) ^ ((r&7)<<4))) = v;
    }
    __syncthreads();
    for (int kk = 0; kk < 4; ++kk) {
      int kb2 = kk*64 + (lane>>4)*16;          // byte offset of k in row
      bf16x8 af[4], bfr[2];
      for (int fi = 0; fi < 4; ++fi) {
        int m = wr*64 + fi*16 + (lane&15);
        af[fi] = *(const bf16x8*)(Al + ((m*256 + kb2) ^ ((m&7)<<4)));
      }
      for (int fj = 0; fj < 2; ++fj) {
        int n = wc*32 + fj*16 + (lane&15);
        bfr[fj] = *(const bf16x8*)(Bl + ((n*256 + kb2) ^ ((n&7)<<4)));
      }
      for (int fi = 0; fi < 4; ++fi)
        for (int fj = 0; fj < 2; ++fj)
          acc[fi][fj] = __builtin_amdgcn_mfma_f32_16x16x32_bf16(af[fi], bfr[fj], acc[fi][fj], 0, 0, 0);
    }
  }
  for (int fi = 0; fi < 4; ++fi)
    for (int fj = 0; fj < 2; ++fj)
      for (int r = 0; r < 4; ++r) {
        int row = wr*64 + fi*16 + (lane>>4)*4 + r;
        int col = wc*32 + fj*16 + (lane&15);
        int n = n0 + col;
        float v = acc[fi][fj][r];
        if (isC0) c0buf[row*256 + n] = v + b_ct[n];
        else      gates[row*1024 + n] = v + b_ih[n] + b_hh[n];
      }
}

// ---------------------------------------------------------------- cell (recomputed) + hN/hK/hV GEMM
__global__ __launch_bounds__(256) void k_mm_hnkv(int di,
    const float* c0buf, const float* gates, const bf16* Wnkvb,
    float* hnkv, float* prev_h, bf16* peh,
    float* histN, float* histK, float* histV) {
  extern __shared__ char smem[];
  char* Al = smem;                 // 128 x 256 bf16, swizzled, row stride 512B
  char* Bl = smem + 65536;         // 64 x 256 bf16
  int blk = blockIdx.x, t = threadIdx.x;
  int n0 = blk*64;
  // prologue: recompute h = cell(c0, gates) directly into LDS (redundant per block; cheap)
  for (int i = t; i < B_*H_; i += 256) {
    int b = i >> 8, k = i & 255;
    float c0v = c0buf[i];
    float gi = gates[b*1024 + k],     gf = gates[b*1024 + 256 + k];
    float gg = gates[b*1024 + 512+k], go = gates[b*1024 + 768 + k];
    float cc = sigf(gf)*c0v + sigf(gi)*tanhf(gg);
    float h  = sigf(go)*tanhf(cc);
    *(bf16*)(Al + ((b*512 + k*2) ^ ((b&7)<<4))) = (bf16)h;
    if (blk == 0) { prev_h[i] = h; peh[b*512 + 256 + k] = (bf16)h; }
  }
  for (int i = t; i < 64*32; i += 256) {
    int r = i >> 5, c8 = i & 31;
    int4 v = *(const int4*)(Wnkvb + (size_t)(n0+r)*H_ + c8*8);
    *(int4*)(Bl + ((r*512 + c8*16) ^ ((r&7)<<4))) = v;
  }
  __syncthreads();
  int wid = t>>6, lane = t&63, wr = wid>>1, wc = wid&1;
  f32x4 acc[4][2] = {};
  for (int kk = 0; kk < 8; ++kk) {
    int kb2 = kk*64 + (lane>>4)*16;
    bf16x8 af[4], bfr[2];
    for (int fi = 0; fi < 4; ++fi) {
      int m = wr*64 + fi*16 + (lane&15);
      af[fi] = *(const bf16x8*)(Al + ((m*512 + kb2) ^ ((m&7)<<4)));
    }
    for (int fj = 0; fj < 2; ++fj) {
      int n = wc*32 + fj*16 + (lane&15);
      bfr[fj] = *(const bf16x8*)(Bl + ((n*512 + kb2) ^ ((n&7)<<4)));
    }
    for (int fi = 0; fi < 4; ++fi)
      for (int fj = 0; fj < 2; ++fj)
        acc[fi][fj] = __builtin_amdgcn_mfma_f32_16x16x32_bf16(af[fi], bfr[fj], acc[fi][fj], 0, 0, 0);
  }
  for (int fi = 0; fi < 4; ++fi)
    for (int fj = 0; fj < 2; ++fj)
      for (int r = 0; r < 4; ++r) {
        int row = wr*64 + fi*16 + (lane>>4)*4 + r;
        int col = n0 + wc*32 + fj*16 + (lane&15);
        float v = acc[fi][fj][r];
        hnkv[row*768 + col] = v;
        float* histT = (col < 256) ? histN : (col < 512) ? histK : histV;
        histT[(row*L_ + di)*H_ + (col & 255)] = v;
      }
}

// ---------------------------------------------------------------- vocab GEMM + streaming LSE (+ posth on blk 0)
__global__ __launch_bounds__(256) void k_mm_nv(int di,
    const float* hnkv, const bf16* Wnvb, const float* b_nv,
    float* pm, float* ps,
    const float* hcur, const float* W_g, const float* b_g,
    float* gt_ws, float* out_g,
    const int* sentence, const float* emb, bf16* peh) {
  extern __shared__ char smem[];
  char* Al = smem;                 // 128 x 256 bf16
  char* Bl = smem + 65536;         // 64 x 256 bf16
  float* red = (float*)(smem + 98304); // 512 floats
  int blk = blockIdx.x, t = threadIdx.x;
  int v0 = blk * 64;
  if (blk == 0) {
    if (t < B_) {
      float d = 0.f;
      for (int k = 0; k < H_; ++k) d += hcur[t*H_ + k] * W_g[k];
      float g = sigf(d + b_g[0]);
      gt_ws[t] = g;
      out_g[t*L_ + di] = g;
    }
    for (int i = t; i < B_*H_; i += 256) {
      int b = i >> 8, k = i & 255;
      int tok = sentence[b*L_ + di];
      peh[b*512 + k] = (bf16)emb[(size_t)tok*H_ + k];
    }
  }
  for (int i = t; i < B_*H_; i += 256) {
    int b = i >> 8, k = i & 255;
    *(bf16*)(Al + ((b*512 + k*2) ^ ((b&7)<<4))) = (bf16)hnkv[b*768 + k];
  }
  for (int i = t; i < 64*32; i += 256) {
    int r = i >> 5, c8 = i & 31;
    int4 v = *(const int4*)(Wnvb + (size_t)(v0+r)*H_ + c8*8);
    *(int4*)(Bl + ((r*512 + c8*16) ^ ((r&7)<<4))) = v;
  }
  __syncthreads();
  int wid = t>>6, lane = t&63, wr = wid>>1, wc = wid&1;
  f32x4 acc[4][2] = {};
  for (int kk = 0; kk < 8; ++kk) {
    int kb2 = kk*64 + (lane>>4)*16;
    bf16x8 af[4], bfr[2];
    for (int fi = 0; fi < 4; ++fi) {
      int m = wr*64 + fi*16 + (lane&15);
      af[fi] = *(const bf16x8*)(Al + ((m*512 + kb2) ^ ((m&7)<<4)));
    }
    for (int fj = 0; fj < 2; ++fj) {
      int n = wc*32 + fj*16 + (lane&15);
      bfr[fj] = *(const bf16x8*)(Bl + ((n*512 + kb2) ^ ((n&7)<<4)));
    }
    for (int fi = 0; fi < 4; ++fi)
      for (int fj = 0; fj < 2; ++fj)
        acc[fi][fj] = __builtin_amdgcn_mfma_f32_16x16x32_bf16(af[fi], bfr[fj], acc[fi][fj], 0, 0, 0);
  }
  float bias[2];
  for (int fj = 0; fj < 2; ++fj) bias[fj] = b_nv[v0 + wc*32 + fj*16 + (lane&15)];
  // phase 1: per-row max over this block's 64 cols
  for (int fi = 0; fi < 4; ++fi)
    for (int r = 0; r < 4; ++r) {
      float v = fmaxf(acc[fi][0][r]+bias[0], acc[fi][1][r]+bias[1]);
      for (int o = 1; o < 16; o <<= 1) v = fmaxf(v, __shfl_xor(v, o));
      if ((lane&15) == 0) red[wc*128 + wr*64 + fi*16 + (lane>>4)*4 + r] = v;
    }
  __syncthreads();
  // phase 2: sum exp with block-wide row max
  for (int fi = 0; fi < 4; ++fi)
    for (int r = 0; r < 4; ++r) {
      int row = wr*64 + fi*16 + (lane>>4)*4 + r;
      float Mx = fmaxf(red[row], red[128+row]);
      float s = __expf(acc[fi][0][r]+bias[0]-Mx) + __expf(acc[fi][1][r]+bias[1]-Mx);
      for (int o = 1; o < 16; o <<= 1) s += __shfl_xor(s, o);
      if ((lane&15) == 0) red[256 + wc*128 + row] = s;
    }
  __syncthreads();
  if (t < B_) {
    float Mx = fmaxf(red[t], red[128+t]);
    pm[blk*B_ + t] = Mx;
    ps[blk*B_ + t] = red[256+t] + red[384+t];
  }
}

// ---------------------------------------------------------------- final: combine step 29 + total loss
__global__ __launch_bounds__(128) void k_final(
    const float* pm, const float* ps, const float* hnkv,
    const float* W_nv, const float* b_nv, const float* gt_ws,
    const int* sentence, const float* loss_arr, float* d_out) {
  __shared__ float s_red[128];
  int t = threadIdx.x;  // = b
  float M = -1e30f, S = 0.f;
  for (int c = 0; c < NCH; ++c) {
    float m = pm[c*B_ + t], s = ps[c*B_ + t];
    float M2 = fmaxf(M, m);
    S = S*__expf(M - M2) + s*__expf(m - M2);
    M = M2;
  }
  int tok = sentence[t*L_ + (L_-1)];
  float zt = b_nv[tok];
  for (int k = 0; k < H_; ++k) zt += hnkv[t*768 + k] * W_nv[(size_t)tok*H_ + k];
  float lb = -(zt - M - __logf(S) + __logf(gt_ws[t]));
  for (int d = 0; d < 28; ++d) lb += loss_arr[d*B_ + t];
  s_red[t] = lb;
  __syncthreads();
  for (int o = 64; o > 0; o >>= 1) {
    if (t < o) s_red[t] += s_red[t + o];
    __syncthreads();
  }
  if (t == 0) d_out[0] = s_red[0];
}

// ---------------------------------------------------------------- launch
extern "C" void kernel_launch(void* const* d_in, const int* in_sizes, int n_in,
                              void* d_out, int out_size, void* d_ws, size_t ws_size,
                              hipStream_t stream) {
  const int* sentence  = (const int*)d_in[0];
  const int* keywords  = (const int*)d_in[1];
  const int* categories= (const int*)d_in[2];
  const int* memsz     = (const int*)d_in[3];
  const float* emb  = (const float*)d_in[5];
  const float* W_ct = (const float*)d_in[6];
  const float* b_ct = (const float*)d_in[7];
  const float* W_ih = (const float*)d_in[8];
  const float* W_hh = (const float*)d_in[9];
  const float* b_ih = (const float*)d_in[10];
  const float* b_hh = (const float*)d_in[11];
  const float* W_n  = (const float*)d_in[12];
  const float* W_k  = (const float*)d_in[13];
  const float* W_v  = (const float*)d_in[14];
  const float* W_nv = (const float*)d_in[15];
  const float* b_nv = (const float*)d_in[16];
  const float* W_g  = (const float*)d_in[17];
  const float* b_g  = (const float*)d_in[18];
  const float* W_hn = (const float*)d_in[19];
  const float* b_hn = (const float*)d_in[20];
  const float* W_hk = (const float*)d_in[21];
  const float* b_hk = (const float*)d_in[22];
  const float* W_hv = (const float*)d_in[23];
  const float* b_hv = (const float*)d_in[24];
  const float* W_mk = (const float*)d_in[25];
  const float* b_mk = (const float*)d_in[26];
  const float* W_mv = (const float*)d_in[27];
  const float* b_mv = (const float*)d_in[28];
  float* out = (float*)d_out;

  char* w = (char*)d_ws;
  size_t off = 0;
  auto alloc = [&](size_t bytes) -> void* {
    void* p = w + off;
    off = (off + bytes + 255) & ~(size_t)255;
    return p;
  };
  float* key_mem = (float*)alloc(B_*M_*H_*4);
  float* val_mem = (float*)alloc(B_*M_*H_*4);
  float* histN   = (float*)alloc((size_t)B_*L_*H_*4);
  float* histK   = (float*)alloc((size_t)B_*L_*H_*4);
  float* histV   = (float*)alloc((size_t)B_*L_*H_*4);
  float* accN    = (float*)alloc(B_*L_*4);
  float* accK    = (float*)alloc(B_*L_*4);
  float* accV    = (float*)alloc(B_*L_*4);
  float* prev_h  = (float*)alloc(B_*H_*4);
  float* hnkv    = (float*)alloc(B_*768*4);
  float* c0buf   = (float*)alloc(B_*H_*4);
  float* gates   = (float*)alloc(B_*1024*4);
  float* gt_ws   = (float*)alloc(B_*4);
  float* pm      = (float*)alloc(NCH*B_*4);
  float* ps      = (float*)alloc(NCH*B_*4);
  float* loss_arr= (float*)alloc(28*B_*4);
  bf16* cat5b  = (bf16*)alloc((size_t)B_*1280*2);
  bf16* peh    = (bf16*)alloc((size_t)B_*512*2);
  bf16* Wctb   = (bf16*)alloc((size_t)256*1280*2);
  bf16* Wihhhb = (bf16*)alloc((size_t)1024*512*2);
  bf16* Wnkvb  = (bf16*)alloc((size_t)768*256*2);
  bf16* Wnvb   = (bf16*)alloc((size_t)VN_*H_*2);

  k_init<<<B_, 256, 0, stream>>>(sentence, keywords, categories, memsz, emb,
      key_mem, val_mem, histN, histK, histV, accN, accK, accV,
      prev_h, peh, out + 1);
  k_conv<<<2048, 256, 0, stream>>>(W_ct, W_ih, W_hh, W_n, W_k, W_v, W_nv,
      Wctb, Wihhhb, Wnkvb, Wnvb);

  AttnP P;
  P.sentence = sentence;
  P.prev_h = prev_h; P.histN = histN; P.histK = histK; P.histV = histV;
  P.accN = accN; P.accK = accK; P.accV = accV;
  P.W_hn = W_hn; P.b_hn = b_hn; P.W_hk = W_hk; P.b_hk = b_hk; P.W_hv = W_hv; P.b_hv = b_hv;
  P.W_mk = W_mk; P.b_mk = b_mk; P.W_mv = W_mv; P.b_mv = b_mv;
  P.key_mem = key_mem; P.val_mem = val_mem;
  P.cat5b = cat5b;
  P.pm = pm; P.ps = ps; P.hnkv = hnkv; P.gt_ws = gt_ws; P.W_nv = W_nv; P.b_nv = b_nv;
  P.loss_arr = loss_arr;

  for (int di = 1; di < L_; ++di) {
    k_attn<<<B_, 256, 0, stream>>>(di, P);
    k_mm_c0g<<<20, 256, 49152, stream>>>(cat5b, peh, Wctb, Wihhhb,
        b_ct, b_ih, b_hh, c0buf, gates);
    k_mm_hnkv<<<12, 256, 98304, stream>>>(di, c0buf, gates, Wnkvb,
        hnkv, prev_h, peh, histN, histK, histV);
    k_mm_nv<<<NCH, 256, 100352, stream>>>(di, hnkv, Wnvb, b_nv, pm, ps,
        prev_h, W_g, b_g, gt_ws, out + 1, sentence, emb, peh);
  }
  k_final<<<1, 128, 0, stream>>>(pm, ps, hnkv, W_nv, b_nv, gt_ws,
      sentence, loss_arr, out);
}

// Round 2
// 4243.969 us; speedup vs baseline: 1.4075x; 1.4075x over previous
//
#include <hip/hip_runtime.h>
#include <math.h>

#define B_ 128
#define L_ 30
#define M_ 10
#define H_ 256
#define VN_ 32000
#define HL_ 7936        // (L+1)*H
#define NCH 500         // VN / 64 chunks for nv gemm

typedef __bf16 bf16;
typedef bf16 bf16x8 __attribute__((ext_vector_type(8)));
typedef float f32x4 __attribute__((ext_vector_type(4)));

__device__ __forceinline__ float rcpf(float x) { return __builtin_amdgcn_rcpf(x); }
__device__ __forceinline__ float sigf(float x) { return rcpf(1.f + __expf(-x)); }
__device__ __forceinline__ float ftanh(float x) {
  float e = __expf(2.f * x);
  return 1.f - 2.f * rcpf(e + 1.f);
}

// ---------------------------------------------------------------- init
__global__ __launch_bounds__(256) void k_init(
    const int* sentence, const int* keywords, const int* categories,
    const int* memsz, const float* emb,
    float* key_mem, float* val_mem,
    float* histN, float* histK, float* histV,
    float* accN, float* accK, float* accV,
    float* prev_h, bf16* peh, float* out_g) {
  int b = blockIdx.x, t = threadIdx.x;   // t in [0,256) == H
  int ms = memsz[b];
  float sk = 0.f, sv = 0.f;
  for (int m = 0; m < M_; ++m) {
    int kw = keywords[b*M_ + m], cg = categories[b*M_ + m];
    float ke = (m < ms) ? emb[(size_t)kw*H_ + t] : 0.f;
    float ve = (m < ms) ? emb[(size_t)cg*H_ + t] : 0.f;
    key_mem[(b*M_ + m)*H_ + t] = ke;
    val_mem[(b*M_ + m)*H_ + t] = ve;
    sk += ke; sv += ve;
  }
  float ih = (sk + sv) / (2.f * (float)ms);
  histN[(b*L_)*H_ + t] = ih;
  histK[(b*L_)*H_ + t] = ih;
  histV[(b*L_)*H_ + t] = ih;
  prev_h[b*H_ + t] = ih;
  peh[b*512 + 256 + t] = (bf16)ih;
  int s0 = sentence[b*L_];
  peh[b*512 + t] = (bf16)emb[(size_t)s0*H_ + t];
  if (t < L_) { accN[b*L_+t] = 0.f; accK[b*L_+t] = 0.f; accV[b*L_+t] = 0.f; }
  if (t == 0) out_g[b*L_] = 0.f;
}

// ---------------------------------------------------------------- weight -> bf16
__global__ __launch_bounds__(256) void k_conv(
    const float* W_ct, const float* W_ih, const float* W_hh,
    const float* W_n, const float* W_k, const float* W_v, const float* W_nv,
    bf16* Wctb, bf16* Wihhhb, bf16* Wnkvb, bf16* Wnvb) {
  int stride = gridDim.x * blockDim.x;
  int base = blockIdx.x * blockDim.x + threadIdx.x;
  for (int i = base; i < 256*1280; i += stride) Wctb[i] = (bf16)W_ct[i];
  for (int i = base; i < 1024*512; i += stride) {
    int n = i >> 9, j = i & 511;
    Wihhhb[i] = (bf16)(j < 256 ? W_ih[n*256 + j] : W_hh[n*256 + j - 256]);
  }
  for (int i = base; i < 768*256; i += stride) {
    int r = i >> 8, k = i & 255;
    const float* src = (r < 256) ? W_n : ((r < 512) ? W_k : W_v);
    Wnkvb[i] = (bf16)src[(r & 255)*256 + k];
  }
  for (int i = base; i < VN_*H_; i += stride) Wnvb[i] = (bf16)W_nv[i];
}

// ---------------------------------------------------------------- attn (+ combine of prev step)
struct AttnP {
  const int* sentence;
  const float *prev_h, *histN, *histK, *histV;
  float *accN, *accK, *accV;
  const float *W_hn, *b_hn, *W_hk, *b_hk, *W_hv, *b_hv;
  const float *W_mk, *b_mk, *W_mv, *b_mv;
  const float *key_mem, *val_mem;
  bf16* cat5b;
  const float *pm, *ps, *hnkv, *gt_ws, *W_nv, *b_nv;
  float* loss_arr;
};

__global__ __launch_bounds__(256) void k_attn(int di, AttnP p) {
  __shared__ float s_ph[H_], s_hp[3][H_], s_w[3][32], s_qm[1024], s_wm[2][16];
  int b = blockIdx.x, t = threadIdx.x;
  int wid = t >> 6, lane = t & 63;

  // ---- combine LSE for step di-1 (wave 3 only) ----
  if (wid == 3 && di > 1) {
    int d = di - 1;
    float M = -1e30f, S = 0.f;
    for (int c = lane; c < NCH; c += 64) {
      float m = p.pm[c*B_ + b], s = p.ps[c*B_ + b];
      float M2 = fmaxf(M, m);
      S = S*__expf(M - M2) + s*__expf(m - M2);
      M = M2;
    }
    for (int o = 1; o < 64; o <<= 1) {
      float Mo = __shfl_xor(M, o), So = __shfl_xor(S, o);
      float M2 = fmaxf(M, Mo);
      S = S*__expf(M - M2) + So*__expf(Mo - M2);
      M = M2;
    }
    int tok = p.sentence[b*L_ + d];
    float zt = 0.f;
    for (int j = 0; j < 4; ++j)
      zt += p.hnkv[b*768 + lane*4 + j] * p.W_nv[(size_t)tok*H_ + lane*4 + j];
    for (int o = 1; o < 64; o <<= 1) zt += __shfl_xor(zt, o);
    if (lane == 0) {
      zt += p.b_nv[tok];
      p.loss_arr[(d-1)*B_ + b] = -(zt - M - __logf(S) + __logf(p.gt_ws[b]));
    }
  }

  // ---- load prev_h + hist slot di-1 ----
  s_ph[t]   = p.prev_h[b*H_ + t];
  s_hp[0][t] = p.histN[(b*L_ + di-1)*H_ + t];
  s_hp[1][t] = p.histK[(b*L_ + di-1)*H_ + t];
  s_hp[2][t] = p.histV[(b*L_ + di-1)*H_ + t];
  __syncthreads();

  // ---- 90 dot pairs: acc update + w logits ----
  const float* Wh0 = p.W_hn; const float* Wh1 = p.W_hk; const float* Wh2 = p.W_hv;
  const float* bh0 = p.b_hn; const float* bh1 = p.b_hk; const float* bh2 = p.b_hv;
  for (int idx = wid; idx < 3*L_; idx += 4) {
    int X = idx / L_, l = idx - X*L_;
    const float* wrow = (X==0 ? Wh0 : X==1 ? Wh1 : Wh2) + l*HL_;
    float dA = 0.f, dB = 0.f;
    for (int j = 0; j < 4; ++j) {
      int k = lane + 64*j;
      dA += s_hp[X][k] * wrow[di*H_ + k];
      dB += s_ph[k]   * wrow[k];
    }
    for (int o = 1; o < 64; o <<= 1) { dA += __shfl_xor(dA, o); dB += __shfl_xor(dB, o); }
    if (lane == 0) {
      float* accA = (X==0 ? p.accN : X==1 ? p.accK : p.accV);
      float a = accA[b*L_ + l] + dA;
      accA[b*L_ + l] = a;
      const float* bh = (X==0 ? bh0 : X==1 ? bh1 : bh2);
      s_w[X][l] = ftanh(a + dB + bh[l]);
    }
  }
  __syncthreads();

  // ---- einsum cH (only slots < di are nonzero) ----
  for (int X = 0; X < 3; ++X) {
    const float* hist = (X==0 ? p.histN : X==1 ? p.histK : p.histV) + (size_t)b*L_*H_;
    float acc = 0.f;
    for (int l = 0; l < di; ++l) acc += s_w[X][l] * hist[l*H_ + t];
    s_qm[256 + X*256 + t] = acc;
  }
  s_qm[t] = s_ph[t];
  __syncthreads();

  // ---- memory attn logits ----
  for (int idx = wid; idx < 2*M_; idx += 4) {
    int X = idx / M_, m = idx - X*M_;
    const float* wrow = (X==0 ? p.W_mk : p.W_mv) + m*1024;
    float d = 0.f;
    for (int j = 0; j < 16; ++j) { int k = lane + 64*j; d += s_qm[k]*wrow[k]; }
    for (int o = 1; o < 64; o <<= 1) d += __shfl_xor(d, o);
    if (lane == 0) s_wm[X][m] = ftanh(d + (X==0 ? p.b_mk : p.b_mv)[m]);
  }
  __syncthreads();

  // ---- cMK/cMV + write cat5 (bf16) ----
  float cmk = 0.f, cmv = 0.f;
  for (int m = 0; m < M_; ++m) {
    cmk += s_wm[0][m] * p.key_mem[(b*M_+m)*H_ + t];
    cmv += s_wm[1][m] * p.val_mem[(b*M_+m)*H_ + t];
  }
  bf16* c5 = p.cat5b + b*1280;
  c5[t]       = (bf16)s_qm[256+t];
  c5[256+t]   = (bf16)s_qm[512+t];
  c5[512+t]   = (bf16)s_qm[768+t];
  c5[768+t]   = (bf16)cmk;
  c5[1024+t]  = (bf16)cmv;
}

// ---------------------------------------------------------------- c0 + gates GEMM (branchy)
__global__ __launch_bounds__(256) void k_mm_c0g(
    const bf16* cat5b, const bf16* peh,
    const bf16* Wctb, const bf16* Wihhhb,
    const float* b_ct, const float* b_ih, const float* b_hh,
    float* c0buf, float* gates) {
  extern __shared__ char smem[];
  char* Al = smem;                 // 128 x 128 bf16, swizzled, row stride 256B
  char* Bl = smem + 32768;         // 64 x 128 bf16
  int blk = blockIdx.x, t = threadIdx.x;
  bool isC0 = blk < 4;
  int n0 = isC0 ? blk*64 : (blk-4)*64;
  int K  = isC0 ? 1280 : 512;
  const bf16* Ap = isC0 ? cat5b : peh;
  const bf16* Bp = (isC0 ? Wctb : Wihhhb) + (size_t)n0*K;
  int wid = t>>6, lane = t&63, wr = wid>>1, wc = wid&1;
  f32x4 acc[4][2] = {};
  for (int kc = 0; kc < K; kc += 128) {
    __syncthreads();
    for (int i = t; i < 128*16; i += 256) {
      int r = i >> 4, c8 = i & 15;
      int4 v = *(const int4*)(Ap + (size_t)r*K + kc + c8*8);
      *(int4*)(Al + ((r*256 + c8*16) ^ ((r&7)<<4))) = v;
    }
    for (int i = t; i < 64*16; i += 256) {
      int r = i >> 4, c8 = i & 15;
      int4 v = *(const int4*)(Bp + (size_t)r*K + kc + c8*8);
      *(int4*)(Bl + ((r*256 + c8*16) ^ ((r&7)<<4))) = v;
    }
    __syncthreads();
    for (int kk = 0; kk < 4; ++kk) {
      int kb2 = kk*64 + (lane>>4)*16;          // byte offset of k in row
      bf16x8 af[4], bfr[2];
      for (int fi = 0; fi < 4; ++fi) {
        int m = wr*64 + fi*16 + (lane&15);
        af[fi] = *(const bf16x8*)(Al + ((m*256 + kb2) ^ ((m&7)<<4)));
      }
      for (int fj = 0; fj < 2; ++fj) {
        int n = wc*32 + fj*16 + (lane&15);
        bfr[fj] = *(const bf16x8*)(Bl + ((n*256 + kb2) ^ ((n&7)<<4)));
      }
      for (int fi = 0; fi < 4; ++fi)
        for (int fj = 0; fj < 2; ++fj)
          acc[fi][fj] = __builtin_amdgcn_mfma_f32_16x16x32_bf16(af[fi], bfr[fj], acc[fi][fj], 0, 0, 0);
    }
  }
  for (int fi = 0; fi < 4; ++fi)
    for (int fj = 0; fj < 2; ++fj)
      for (int r = 0; r < 4; ++r) {
        int row = wr*64 + fi*16 + (lane>>4)*4 + r;
        int col = wc*32 + fj*16 + (lane&15);
        int n = n0 + col;
        float v = acc[fi][fj][r];
        if (isC0) c0buf[row*256 + n] = v + b_ct[n];
        else      gates[row*1024 + n] = v + b_ih[n] + b_hh[n];
      }
}

// ---------------------------------------------------------------- LSTM cell (once, fast transcendentals)
__global__ __launch_bounds__(256) void k_cell(
    const float* c0buf, const float* gates,
    float* prev_h, bf16* hb, bf16* peh) {
  int i = blockIdx.x*256 + threadIdx.x;   // 0..32767
  int b = i >> 8, k = i & 255;
  float c0v = c0buf[i];
  float gi = gates[b*1024 + k],       gf = gates[b*1024 + 256 + k];
  float gg = gates[b*1024 + 512 + k], go = gates[b*1024 + 768 + k];
  float cc = sigf(gf)*c0v + sigf(gi)*ftanh(gg);
  float h  = sigf(go)*ftanh(cc);
  prev_h[i] = h;
  hb[i] = (bf16)h;
  peh[b*512 + 256 + k] = (bf16)h;
}

// ---------------------------------------------------------------- hN/hK/hV GEMM (pure)
__global__ __launch_bounds__(256) void k_mm_hnkv(int di,
    const bf16* hb, const bf16* Wnkvb,
    float* hnkv, bf16* hNb,
    float* histN, float* histK, float* histV) {
  extern __shared__ char smem[];
  char* Al = smem;                 // 128 x 256 bf16, swizzled, row stride 512B
  char* Bl = smem + 65536;         // 64 x 256 bf16
  int blk = blockIdx.x, t = threadIdx.x;
  int n0 = blk*64;
  for (int i = t; i < 128*32; i += 256) {
    int r = i >> 5, c8 = i & 31;
    int4 v = *(const int4*)(hb + (size_t)r*H_ + c8*8);
    *(int4*)(Al + ((r*512 + c8*16) ^ ((r&7)<<4))) = v;
  }
  for (int i = t; i < 64*32; i += 256) {
    int r = i >> 5, c8 = i & 31;
    int4 v = *(const int4*)(Wnkvb + (size_t)(n0+r)*H_ + c8*8);
    *(int4*)(Bl + ((r*512 + c8*16) ^ ((r&7)<<4))) = v;
  }
  __syncthreads();
  int wid = t>>6, lane = t&63, wr = wid>>1, wc = wid&1;
  f32x4 acc[4][2] = {};
  for (int kk = 0; kk < 8; ++kk) {
    int kb2 = kk*64 + (lane>>4)*16;
    bf16x8 af[4], bfr[2];
    for (int fi = 0; fi < 4; ++fi) {
      int m = wr*64 + fi*16 + (lane&15);
      af[fi] = *(const bf16x8*)(Al + ((m*512 + kb2) ^ ((m&7)<<4)));
    }
    for (int fj = 0; fj < 2; ++fj) {
      int n = wc*32 + fj*16 + (lane&15);
      bfr[fj] = *(const bf16x8*)(Bl + ((n*512 + kb2) ^ ((n&7)<<4)));
    }
    for (int fi = 0; fi < 4; ++fi)
      for (int fj = 0; fj < 2; ++fj)
        acc[fi][fj] = __builtin_amdgcn_mfma_f32_16x16x32_bf16(af[fi], bfr[fj], acc[fi][fj], 0, 0, 0);
  }
  for (int fi = 0; fi < 4; ++fi)
    for (int fj = 0; fj < 2; ++fj)
      for (int r = 0; r < 4; ++r) {
        int row = wr*64 + fi*16 + (lane>>4)*4 + r;
        int col = n0 + wc*32 + fj*16 + (lane&15);
        float v = acc[fi][fj][r];
        hnkv[row*768 + col] = v;
        float* histT = (col < 256) ? histN : (col < 512) ? histK : histV;
        histT[(row*L_ + di)*H_ + (col & 255)] = v;
        if (col < 256) hNb[row*256 + col] = (bf16)v;
      }
}

// ---------------------------------------------------------------- vocab GEMM + streaming LSE (+ posth on blk 0)
__global__ __launch_bounds__(256) void k_mm_nv(int di,
    const bf16* hNb, const bf16* Wnvb, const float* b_nv,
    float* pm, float* ps,
    const float* hcur, const float* W_g, const float* b_g,
    float* gt_ws, float* out_g,
    const int* sentence, const float* emb, bf16* peh) {
  extern __shared__ char smem[];
  char* Al = smem;                 // 128 x 256 bf16
  char* Bl = smem + 65536;         // 64 x 256 bf16
  float* red = (float*)(smem + 98304); // 512 floats
  int blk = blockIdx.x, t = threadIdx.x;
  int v0 = blk * 64;
  if (blk == 0) {
    if (t < B_) {
      float d = 0.f;
      for (int k = 0; k < H_; ++k) d += hcur[t*H_ + k] * W_g[k];
      float g = sigf(d + b_g[0]);
      gt_ws[t] = g;
      out_g[t*L_ + di] = g;
    }
    for (int i = t; i < B_*H_; i += 256) {
      int b = i >> 8, k = i & 255;
      int tok = sentence[b*L_ + di];
      peh[b*512 + k] = (bf16)emb[(size_t)tok*H_ + k];
    }
  }
  for (int i = t; i < 128*32; i += 256) {
    int r = i >> 5, c8 = i & 31;
    int4 v = *(const int4*)(hNb + (size_t)r*H_ + c8*8);
    *(int4*)(Al + ((r*512 + c8*16) ^ ((r&7)<<4))) = v;
  }
  for (int i = t; i < 64*32; i += 256) {
    int r = i >> 5, c8 = i & 31;
    int4 v = *(const int4*)(Wnvb + (size_t)(v0+r)*H_ + c8*8);
    *(int4*)(Bl + ((r*512 + c8*16) ^ ((r&7)<<4))) = v;
  }
  __syncthreads();
  int wid = t>>6, lane = t&63, wr = wid>>1, wc = wid&1;
  f32x4 acc[4][2] = {};
  for (int kk = 0; kk < 8; ++kk) {
    int kb2 = kk*64 + (lane>>4)*16;
    bf16x8 af[4], bfr[2];
    for (int fi = 0; fi < 4; ++fi) {
      int m = wr*64 + fi*16 + (lane&15);
      af[fi] = *(const bf16x8*)(Al + ((m*512 + kb2) ^ ((m&7)<<4)));
    }
    for (int fj = 0; fj < 2; ++fj) {
      int n = wc*32 + fj*16 + (lane&15);
      bfr[fj] = *(const bf16x8*)(Bl + ((n*512 + kb2) ^ ((n&7)<<4)));
    }
    for (int fi = 0; fi < 4; ++fi)
      for (int fj = 0; fj < 2; ++fj)
        acc[fi][fj] = __builtin_amdgcn_mfma_f32_16x16x32_bf16(af[fi], bfr[fj], acc[fi][fj], 0, 0, 0);
  }
  float bias[2];
  for (int fj = 0; fj < 2; ++fj) bias[fj] = b_nv[v0 + wc*32 + fj*16 + (lane&15)];
  // phase 1: per-row max over this block's 64 cols
  for (int fi = 0; fi < 4; ++fi)
    for (int r = 0; r < 4; ++r) {
      float v = fmaxf(acc[fi][0][r]+bias[0], acc[fi][1][r]+bias[1]);
      for (int o = 1; o < 16; o <<= 1) v = fmaxf(v, __shfl_xor(v, o));
      if ((lane&15) == 0) red[wc*128 + wr*64 + fi*16 + (lane>>4)*4 + r] = v;
    }
  __syncthreads();
  // phase 2: sum exp with block-wide row max
  for (int fi = 0; fi < 4; ++fi)
    for (int r = 0; r < 4; ++r) {
      int row = wr*64 + fi*16 + (lane>>4)*4 + r;
      float Mx = fmaxf(red[row], red[128+row]);
      float s = __expf(acc[fi][0][r]+bias[0]-Mx) + __expf(acc[fi][1][r]+bias[1]-Mx);
      for (int o = 1; o < 16; o <<= 1) s += __shfl_xor(s, o);
      if ((lane&15) == 0) red[256 + wc*128 + row] = s;
    }
  __syncthreads();
  if (t < B_) {
    float Mx = fmaxf(red[t], red[128+t]);
    pm[blk*B_ + t] = Mx;
    ps[blk*B_ + t] = red[256+t] + red[384+t];
  }
}

// ---------------------------------------------------------------- final: combine step 29 + total loss
__global__ __launch_bounds__(128) void k_final(
    const float* pm, const float* ps, const float* hnkv,
    const float* W_nv, const float* b_nv, const float* gt_ws,
    const int* sentence, const float* loss_arr, float* d_out) {
  __shared__ float s_red[128];
  int t = threadIdx.x;  // = b
  float M = -1e30f, S = 0.f;
  for (int c = 0; c < NCH; ++c) {
    float m = pm[c*B_ + t], s = ps[c*B_ + t];
    float M2 = fmaxf(M, m);
    S = S*__expf(M - M2) + s*__expf(m - M2);
    M = M2;
  }
  int tok = sentence[t*L_ + (L_-1)];
  float zt = b_nv[tok];
  for (int k = 0; k < H_; ++k) zt += hnkv[t*768 + k] * W_nv[(size_t)tok*H_ + k];
  float lb = -(zt - M - __logf(S) + __logf(gt_ws[t]));
  for (int d = 0; d < 28; ++d) lb += loss_arr[d*B_ + t];
  s_red[t] = lb;
  __syncthreads();
  for (int o = 64; o > 0; o >>= 1) {
    if (t < o) s_red[t] += s_red[t + o];
    __syncthreads();
  }
  if (t == 0) d_out[0] = s_red[0];
}

// ---------------------------------------------------------------- launch
extern "C" void kernel_launch(void* const* d_in, const int* in_sizes, int n_in,
                              void* d_out, int out_size, void* d_ws, size_t ws_size,
                              hipStream_t stream) {
  const int* sentence  = (const int*)d_in[0];
  const int* keywords  = (const int*)d_in[1];
  const int* categories= (const int*)d_in[2];
  const int* memsz     = (const int*)d_in[3];
  const float* emb  = (const float*)d_in[5];
  const float* W_ct = (const float*)d_in[6];
  const float* b_ct = (const float*)d_in[7];
  const float* W_ih = (const float*)d_in[8];
  const float* W_hh = (const float*)d_in[9];
  const float* b_ih = (const float*)d_in[10];
  const float* b_hh = (const float*)d_in[11];
  const float* W_n  = (const float*)d_in[12];
  const float* W_k  = (const float*)d_in[13];
  const float* W_v  = (const float*)d_in[14];
  const float* W_nv = (const float*)d_in[15];
  const float* b_nv = (const float*)d_in[16];
  const float* W_g  = (const float*)d_in[17];
  const float* b_g  = (const float*)d_in[18];
  const float* W_hn = (const float*)d_in[19];
  const float* b_hn = (const float*)d_in[20];
  const float* W_hk = (const float*)d_in[21];
  const float* b_hk = (const float*)d_in[22];
  const float* W_hv = (const float*)d_in[23];
  const float* b_hv = (const float*)d_in[24];
  const float* W_mk = (const float*)d_in[25];
  const float* b_mk = (const float*)d_in[26];
  const float* W_mv = (const float*)d_in[27];
  const float* b_mv = (const float*)d_in[28];
  float* out = (float*)d_out;

  char* w = (char*)d_ws;
  size_t off = 0;
  auto alloc = [&](size_t bytes) -> void* {
    void* p = w + off;
    off = (off + bytes + 255) & ~(size_t)255;
    return p;
  };
  float* key_mem = (float*)alloc(B_*M_*H_*4);
  float* val_mem = (float*)alloc(B_*M_*H_*4);
  float* histN   = (float*)alloc((size_t)B_*L_*H_*4);
  float* histK   = (float*)alloc((size_t)B_*L_*H_*4);
  float* histV   = (float*)alloc((size_t)B_*L_*H_*4);
  float* accN    = (float*)alloc(B_*L_*4);
  float* accK    = (float*)alloc(B_*L_*4);
  float* accV    = (float*)alloc(B_*L_*4);
  float* prev_h  = (float*)alloc(B_*H_*4);
  float* hnkv    = (float*)alloc(B_*768*4);
  float* c0buf   = (float*)alloc(B_*H_*4);
  float* gates   = (float*)alloc(B_*1024*4);
  float* gt_ws   = (float*)alloc(B_*4);
  float* pm      = (float*)alloc(NCH*B_*4);
  float* ps      = (float*)alloc(NCH*B_*4);
  float* loss_arr= (float*)alloc(28*B_*4);
  bf16* cat5b  = (bf16*)alloc((size_t)B_*1280*2);
  bf16* peh    = (bf16*)alloc((size_t)B_*512*2);
  bf16* hb     = (bf16*)alloc((size_t)B_*H_*2);
  bf16* hNb    = (bf16*)alloc((size_t)B_*H_*2);
  bf16* Wctb   = (bf16*)alloc((size_t)256*1280*2);
  bf16* Wihhhb = (bf16*)alloc((size_t)1024*512*2);
  bf16* Wnkvb  = (bf16*)alloc((size_t)768*256*2);
  bf16* Wnvb   = (bf16*)alloc((size_t)VN_*H_*2);

  k_init<<<B_, 256, 0, stream>>>(sentence, keywords, categories, memsz, emb,
      key_mem, val_mem, histN, histK, histV, accN, accK, accV,
      prev_h, peh, out + 1);
  k_conv<<<2048, 256, 0, stream>>>(W_ct, W_ih, W_hh, W_n, W_k, W_v, W_nv,
      Wctb, Wihhhb, Wnkvb, Wnvb);

  AttnP P;
  P.sentence = sentence;
  P.prev_h = prev_h; P.histN = histN; P.histK = histK; P.histV = histV;
  P.accN = accN; P.accK = accK; P.accV = accV;
  P.W_hn = W_hn; P.b_hn = b_hn; P.W_hk = W_hk; P.b_hk = b_hk; P.W_hv = W_hv; P.b_hv = b_hv;
  P.W_mk = W_mk; P.b_mk = b_mk; P.W_mv = W_mv; P.b_mv = b_mv;
  P.key_mem = key_mem; P.val_mem = val_mem;
  P.cat5b = cat5b;
  P.pm = pm; P.ps = ps; P.hnkv = hnkv; P.gt_ws = gt_ws; P.W_nv = W_nv; P.b_nv = b_nv;
  P.loss_arr = loss_arr;

  for (int di = 1; di < L_; ++di) {
    k_attn<<<B_, 256, 0, stream>>>(di, P);
    k_mm_c0g<<<20, 256, 49152, stream>>>(cat5b, peh, Wctb, Wihhhb,
        b_ct, b_ih, b_hh, c0buf, gates);
    k_cell<<<128, 256, 0, stream>>>(c0buf, gates, prev_h, hb, peh);
    k_mm_hnkv<<<12, 256, 98304, stream>>>(di, hb, Wnkvb,
        hnkv, hNb, histN, histK, histV);
    k_mm_nv<<<NCH, 256, 100352, stream>>>(di, hNb, Wnvb, b_nv, pm, ps,
        prev_h, W_g, b_g, gt_ws, out + 1, sentence, emb, peh);
  }
  k_final<<<1, 128, 0, stream>>>(pm, ps, hnkv, W_nv, b_nv, gt_ws,
      sentence, loss_arr, out);
}

// Round 3
// 1901.209 us; speedup vs baseline: 3.1418x; 2.2322x over previous
//
#include <hip/hip_runtime.h>
#include <math.h>

#define B_ 128
#define L_ 30
#define M_ 10
#define H_ 256
#define VN_ 32000
#define VCH 5        // vocab N-chunks per tile
#define VITER 50     // (VN/VCH)/128

typedef __bf16 bf16;
typedef bf16 bf16x8 __attribute__((ext_vector_type(8)));
typedef float f32x4 __attribute__((ext_vector_type(4)));

__device__ __forceinline__ float rcpf(float x) { return __builtin_amdgcn_rcpf(x); }
__device__ __forceinline__ float sigf(float x) { return rcpf(1.f + __expf(-x)); }
__device__ __forceinline__ float ftanh(float x) {
  float e = __expf(2.f * x);
  return 1.f - 2.f * rcpf(e + 1.f);
}
__device__ __forceinline__ float u2lo(unsigned w) { return __builtin_bit_cast(float, w << 16); }
__device__ __forceinline__ float u2hi(unsigned w) { return __builtin_bit_cast(float, w & 0xffff0000u); }
__device__ __forceinline__ unsigned packbf2(float a, float b) {
  unsigned short lo = __builtin_bit_cast(unsigned short, (bf16)a);
  unsigned short hi = __builtin_bit_cast(unsigned short, (bf16)b);
  return (unsigned)lo | ((unsigned)hi << 16);
}

// ---------------------------------------------------------------- weight prep
// WctTp  u32[1280][128]: pair(n=2p,2p+1) of W_ct^T       (c0 = cat5 . W_ct^T)
// WihhTp u32[512][512] : pair of [W_ih|W_hh]^T over x2=[pe,h]
// WnkvTp u32[256][384] : pair of [W_n;W_k;W_v]^T
// Whb bf16[90][7936], Wmb bf16[20][1024], Wnvb bf16[32000][256]
__global__ __launch_bounds__(256) void k_prep(
    const float* W_ct, const float* W_ih, const float* W_hh,
    const float* W_n, const float* W_k, const float* W_v, const float* W_nv,
    const float* W_hn, const float* W_hk, const float* W_hv,
    const float* W_mk, const float* W_mv,
    unsigned* WctTp, unsigned* WihhTp, unsigned* WnkvTp,
    bf16* Whb, bf16* Wmb, bf16* Wnvb) {
  int stride = gridDim.x * blockDim.x;
  int base = blockIdx.x * blockDim.x + threadIdx.x;
  for (int i = base; i < 1280*128; i += stride) {
    int k = i >> 7, p = i & 127;
    WctTp[i] = packbf2(W_ct[(2*p)*1280 + k], W_ct[(2*p+1)*1280 + k]);
  }
  for (int i = base; i < 512*512; i += stride) {
    int k = i >> 9, p = i & 511;
    int n0 = 2*p;
    float a = (k < 256) ? W_ih[n0*256 + k]     : W_hh[n0*256 + k - 256];
    float b = (k < 256) ? W_ih[(n0+1)*256 + k] : W_hh[(n0+1)*256 + k - 256];
    WihhTp[i] = packbf2(a, b);
  }
  for (int i = base; i < 256*384; i += stride) {
    int k = i / 384, p = i - k*384;
    int n0 = 2*p;
    const float* s0 = (n0 < 256) ? W_n : (n0 < 512) ? W_k : W_v;
    float a = s0[(n0 & 255)*256 + k];
    float b = s0[((n0+1) & 255)*256 + k];
    WnkvTp[i] = packbf2(a, b);
  }
  for (int i = base; i < 30*7936; i += stride) {
    Whb[i]            = (bf16)W_hn[i];
    Whb[238080 + i]   = (bf16)W_hk[i];
    Whb[476160 + i]   = (bf16)W_hv[i];
  }
  for (int i = base; i < 10240; i += stride) {
    Wmb[i]         = (bf16)W_mk[i];
    Wmb[10240 + i] = (bf16)W_mv[i];
  }
  for (int i = base; i < VN_*H_; i += stride) Wnvb[i] = (bf16)W_nv[i];
}

// ---------------------------------------------------------------- full recurrence, one block per batch element
struct LoopP {
  const int *sentence, *keywords, *categories, *memsz;
  const float *emb;
  const unsigned *WctTp, *WihhTp, *WnkvTp;
  const bf16 *Whb, *Wmb;
  const float *b_ct, *b_ih, *b_hh, *b_hn, *b_hk, *b_hv, *b_mk, *b_mv, *W_g, *b_g;
  bf16* hNb;       // [29*128][256]
  float* gt_all;   // [29*128]
  float* outg;     // [128][30]
};

__global__ __launch_bounds__(512) void k_loop(LoopP p) {
  extern __shared__ float S[];
  float* hist = S;              // [3][30][256]
  float* memb = S + 23040;      // [2][10][256]
  float* peph = S + 28160;      // [512]: [prev_emb, prev_h]
  float* buf  = S + 28672;      // [1536]: [prev_h, cHN,cHK,cHV, cMK,cMV]
  float* gate = S + 30208;      // [1024]
  float* hs   = S + 31232;      // [256]
  float* part = S + 31488;      // [4][256]
  float* sw   = S + 32512;      // [3][32]
  float* swm  = S + 32608;      // [32]
  float* acA  = S + 32640;      // [3][32]
  int b = blockIdx.x, t = threadIdx.x;
  int wid = t >> 6, lane = t & 63;

  // ---- init ----
  if (t < 256) {
    int ms = p.memsz[b];
    float sk = 0.f, sv = 0.f;
    for (int m = 0; m < M_; ++m) {
      int kw = p.keywords[b*M_ + m], cg = p.categories[b*M_ + m];
      float ke = (m < ms) ? p.emb[(size_t)kw*H_ + t] : 0.f;
      float ve = (m < ms) ? p.emb[(size_t)cg*H_ + t] : 0.f;
      memb[m*256 + t] = ke; memb[2560 + m*256 + t] = ve;
      sk += ke; sv += ve;
    }
    float ih = (sk + sv) / (2.f * (float)ms);
    hist[t] = ih; hist[7680 + t] = ih; hist[15360 + t] = ih;
    peph[256 + t] = ih;
    int s0 = p.sentence[b*L_];
    peph[t] = p.emb[(size_t)s0*H_ + t];
  }
  if (t < 96) acA[t] = 0.f;
  if (t == 0) p.outg[b*L_] = 0.f;
  __syncthreads();

  for (int di = 1; di < L_; ++di) {
    // ---- A: gates GEVM (all threads) + attn logits (wave-strided) ----
    {
      float a0 = 0.f, a1 = 0.f;
      const unsigned* wp = p.WihhTp + t;
      #pragma unroll 4
      for (int k4 = 0; k4 < 128; ++k4) {
        float4 x4 = *(const float4*)&peph[4*k4];
        unsigned w0 = wp[0], w1 = wp[512], w2 = wp[1024], w3 = wp[1536];
        wp += 2048;
        a0 = fmaf(x4.x, u2lo(w0), a0); a1 = fmaf(x4.x, u2hi(w0), a1);
        a0 = fmaf(x4.y, u2lo(w1), a0); a1 = fmaf(x4.y, u2hi(w1), a1);
        a0 = fmaf(x4.z, u2lo(w2), a0); a1 = fmaf(x4.z, u2hi(w2), a1);
        a0 = fmaf(x4.w, u2lo(w3), a0); a1 = fmaf(x4.w, u2hi(w3), a1);
      }
      gate[2*t] = a0; gate[2*t + 1] = a1;
    }
    for (int pr = wid; pr < 90; pr += 8) {
      int X = pr / 30, l = pr - X*30;
      const bf16* wr = p.Whb + (size_t)(X*30 + l)*7936;
      const float* hp = hist + X*7680 + (di-1)*256;
      float dA = 0.f, dB = 0.f;
      #pragma unroll
      for (int j = 0; j < 4; ++j) {
        int k = lane + 64*j;
        dA = fmaf(hp[k], (float)wr[di*256 + k], dA);
        dB = fmaf(peph[256 + k], (float)wr[k], dB);
      }
      for (int o = 1; o < 64; o <<= 1) { dA += __shfl_xor(dA, o); dB += __shfl_xor(dB, o); }
      if (lane == 0) {
        const float* bh = (X == 0) ? p.b_hn : (X == 1) ? p.b_hk : p.b_hv;
        float a = acA[X*32 + l] + dA;
        acA[X*32 + l] = a;
        sw[X*32 + l] = ftanh(a + dB + bh[l]);
      }
    }
    __syncthreads();
    // ---- B: einsum cH (slots < di) + qm prev_h copy ----
    {
      int X = t >> 8, k = t & 255;
      float a = 0.f;
      const float* hp = hist + X*7680;
      for (int l = 0; l < di; ++l) a = fmaf(sw[X*32 + l], hp[l*256 + k], a);
      buf[256 + t] = a;
      if (t < 256) {
        float a2 = 0.f;
        const float* hp2 = hist + 15360;
        for (int l = 0; l < di; ++l) a2 = fmaf(sw[64 + l], hp2[l*256 + t], a2);
        buf[768 + t] = a2;
        buf[t] = peph[256 + t];
      }
    }
    __syncthreads();
    // ---- C: memory-attn logits ----
    for (int pr = wid; pr < 20; pr += 8) {
      int X = pr / 10, m = pr - X*10;
      const bf16* wr = p.Wmb + (size_t)(X*10 + m)*1024;
      float d = 0.f;
      #pragma unroll
      for (int j = 0; j < 16; ++j) { int k = lane + 64*j; d = fmaf(buf[k], (float)wr[k], d); }
      for (int o = 1; o < 64; o <<= 1) d += __shfl_xor(d, o);
      if (lane == 0) {
        const float* bm = (X == 0) ? p.b_mk : p.b_mv;
        swm[X*16 + m] = ftanh(d + bm[m]);
      }
    }
    __syncthreads();
    // ---- D: cMK/cMV ----
    {
      int X = t >> 8, k = t & 255;
      float c = 0.f;
      const float* mm = memb + X*2560;
      #pragma unroll
      for (int m = 0; m < M_; ++m) c = fmaf(swm[X*16 + m], mm[m*256 + k], c);
      buf[1024 + t] = c;
    }
    __syncthreads();
    // ---- E: c0 GEVM partials (K split 4) ----
    {
      int pp = t & 127, kq = t >> 7;
      float a0 = 0.f, a1 = 0.f;
      const unsigned* wp = p.WctTp + (size_t)(kq*320)*128 + pp;
      const float* xb = buf + 256 + kq*320;
      #pragma unroll 4
      for (int k4 = 0; k4 < 80; ++k4) {
        float4 x4 = *(const float4*)&xb[4*k4];
        unsigned w0 = wp[0], w1 = wp[128], w2 = wp[256], w3 = wp[384];
        wp += 512;
        a0 = fmaf(x4.x, u2lo(w0), a0); a1 = fmaf(x4.x, u2hi(w0), a1);
        a0 = fmaf(x4.y, u2lo(w1), a0); a1 = fmaf(x4.y, u2hi(w1), a1);
        a0 = fmaf(x4.z, u2lo(w2), a0); a1 = fmaf(x4.z, u2hi(w2), a1);
        a0 = fmaf(x4.w, u2lo(w3), a0); a1 = fmaf(x4.w, u2hi(w3), a1);
      }
      part[kq*256 + 2*pp] = a0; part[kq*256 + 2*pp + 1] = a1;
    }
    __syncthreads();
    // ---- F: cell + next-step inputs ----
    if (t < 256) {
      float c0v = p.b_ct[t] + part[t] + part[256 + t] + part[512 + t] + part[768 + t];
      float bi = p.b_ih[t] + p.b_hh[t];
      float bf_ = p.b_ih[256 + t] + p.b_hh[256 + t];
      float bg = p.b_ih[512 + t] + p.b_hh[512 + t];
      float bo = p.b_ih[768 + t] + p.b_hh[768 + t];
      float gi = gate[t] + bi, gf = gate[256 + t] + bf_;
      float gg = gate[512 + t] + bg, go = gate[768 + t] + bo;
      float cc = sigf(gf)*c0v + sigf(gi)*ftanh(gg);
      float h = sigf(go)*ftanh(cc);
      hs[t] = h;
      peph[256 + t] = h;
      int tok = p.sentence[b*L_ + di];
      peph[t] = p.emb[(size_t)tok*H_ + t];
    }
    __syncthreads();
    // ---- G: hN/hK/hV GEVM + gt ----
    if (t < 384) {
      float a0 = 0.f, a1 = 0.f;
      const unsigned* wp = p.WnkvTp + t;
      #pragma unroll 4
      for (int k4 = 0; k4 < 64; ++k4) {
        float4 x4 = *(const float4*)&hs[4*k4];
        unsigned w0 = wp[0], w1 = wp[384], w2 = wp[768], w3 = wp[1152];
        wp += 1536;
        a0 = fmaf(x4.x, u2lo(w0), a0); a1 = fmaf(x4.x, u2hi(w0), a1);
        a0 = fmaf(x4.y, u2lo(w1), a0); a1 = fmaf(x4.y, u2hi(w1), a1);
        a0 = fmaf(x4.z, u2lo(w2), a0); a1 = fmaf(x4.z, u2hi(w2), a1);
        a0 = fmaf(x4.w, u2lo(w3), a0); a1 = fmaf(x4.w, u2hi(w3), a1);
      }
      int n0 = 2*t;
      int X = n0 >> 8, j0 = n0 & 255;
      hist[X*7680 + di*256 + j0] = a0;
      hist[X*7680 + di*256 + j0 + 1] = a1;
      if (X == 0)
        *(unsigned*)(p.hNb + ((size_t)(di-1)*B_ + b)*H_ + j0) = packbf2(a0, a1);
    } else if (t >= 448) {
      int l2 = t - 448;
      float d = 0.f;
      #pragma unroll
      for (int j = 0; j < 4; ++j) { int k = l2 + 64*j; d = fmaf(hs[k], p.W_g[k], d); }
      for (int o = 1; o < 64; o <<= 1) d += __shfl_xor(d, o);
      if (l2 == 0) {
        float g = sigf(d + p.b_g[0]);
        p.gt_all[(di-1)*B_ + b] = g;
        p.outg[b*L_ + di] = g;
      }
    }
    __syncthreads();
  }
}

// ---------------------------------------------------------------- batched vocab GEMM + streaming LSE
__global__ __launch_bounds__(256) void k_vocab(
    const bf16* hNb, const bf16* Wnvb, const float* b_nv, float2* pmps) {
  extern __shared__ char sm[];
  char* Al = sm;             // 128 x 256 bf16, swizzled
  char* Bl = sm + 65536;     // 128 x 256 bf16, swizzled
  int blk = blockIdx.x;
  int tile = blk / VCH, ch = blk - tile*VCH;
  int t = threadIdx.x, wid = t >> 6, lane = t & 63;
  // stage A (this tile's 128 hN rows)
  for (int i = t; i < 128*32; i += 256) {
    int r = i >> 5, c8 = i & 31;
    int4 v = *(const int4*)(hNb + ((size_t)tile*128 + r)*H_ + c8*8);
    *(int4*)(Al + ((r*512 + c8*16) ^ ((r&7)<<4))) = v;
  }
  __syncthreads();
  // A fragments fully in registers
  bf16x8 afr[8][2];
  #pragma unroll
  for (int kk = 0; kk < 8; ++kk) {
    int kb2 = kk*64 + (lane>>4)*16;
    #pragma unroll
    for (int fi = 0; fi < 2; ++fi) {
      int m = wid*32 + fi*16 + (lane & 15);
      afr[kk][fi] = *(const bf16x8*)(Al + ((m*512 + kb2) ^ ((m&7)<<4)));
    }
  }
  float Mrun[2][4], Srun[2][4];
  #pragma unroll
  for (int fi = 0; fi < 2; ++fi)
    #pragma unroll
    for (int r = 0; r < 4; ++r) { Mrun[fi][r] = -1e30f; Srun[fi][r] = 0.f; }
  int v0 = ch * (VN_/VCH);
  for (int it = 0; it < VITER; ++it) {
    // stage B chunk (128 vocab rows)
    for (int i = t; i < 128*32; i += 256) {
      int r = i >> 5, c8 = i & 31;
      int4 v = *(const int4*)(Wnvb + (size_t)(v0 + it*128 + r)*H_ + c8*8);
      *(int4*)(Bl + ((r*512 + c8*16) ^ ((r&7)<<4))) = v;
    }
    __syncthreads();
    f32x4 acc[2][8] = {};
    #pragma unroll
    for (int kk = 0; kk < 8; ++kk) {
      int kb2 = kk*64 + (lane>>4)*16;
      bf16x8 bfr[8];
      #pragma unroll
      for (int fj = 0; fj < 8; ++fj) {
        int n = fj*16 + (lane & 15);
        bfr[fj] = *(const bf16x8*)(Bl + ((n*512 + kb2) ^ ((n&7)<<4)));
      }
      #pragma unroll
      for (int fi = 0; fi < 2; ++fi)
        #pragma unroll
        for (int fj = 0; fj < 8; ++fj)
          acc[fi][fj] = __builtin_amdgcn_mfma_f32_16x16x32_bf16(afr[kk][fi], bfr[fj], acc[fi][fj], 0, 0, 0);
    }
    float bb[8];
    #pragma unroll
    for (int fj = 0; fj < 8; ++fj) bb[fj] = b_nv[v0 + it*128 + fj*16 + (lane & 15)];
    #pragma unroll
    for (int fi = 0; fi < 2; ++fi)
      #pragma unroll
      for (int r = 0; r < 4; ++r) {
        float mi = acc[fi][0][r] + bb[0];
        #pragma unroll
        for (int fj = 1; fj < 8; ++fj) mi = fmaxf(mi, acc[fi][fj][r] + bb[fj]);
        for (int o = 1; o < 16; o <<= 1) mi = fmaxf(mi, __shfl_xor(mi, o));
        float si = 0.f;
        #pragma unroll
        for (int fj = 0; fj < 8; ++fj) si += __expf(acc[fi][fj][r] + bb[fj] - mi);
        for (int o = 1; o < 16; o <<= 1) si += __shfl_xor(si, o);
        float M2 = fmaxf(Mrun[fi][r], mi);
        Srun[fi][r] = Srun[fi][r]*__expf(Mrun[fi][r] - M2) + si*__expf(mi - M2);
        Mrun[fi][r] = M2;
      }
    __syncthreads();
  }
  #pragma unroll
  for (int fi = 0; fi < 2; ++fi)
    #pragma unroll
    for (int r = 0; r < 4; ++r)
      if ((lane & 15) == 0) {
        int row = wid*32 + fi*16 + (lane>>4)*4 + r;
        int g = tile*128 + row;
        pmps[(size_t)g*VCH + ch] = make_float2(Mrun[fi][r], Srun[fi][r]);
      }
}

// ---------------------------------------------------------------- per-row loss
__global__ __launch_bounds__(128) void k_combine(
    const float2* pmps, const bf16* hNb, const float* W_nv, const float* b_nv,
    const float* gt_all, const int* sentence, float* loss_part) {
  __shared__ float red[128];
  int tile = blockIdx.x, bb = threadIdx.x;
  int g = tile*128 + bb;
  float M = -1e30f, Ssum = 0.f;
  #pragma unroll
  for (int c = 0; c < VCH; ++c) {
    float2 v = pmps[(size_t)g*VCH + c];
    float M2 = fmaxf(M, v.x);
    Ssum = Ssum*__expf(M - M2) + v.y*__expf(v.x - M2);
    M = M2;
  }
  int tok = sentence[bb*L_ + tile + 1];
  float z = b_nv[tok];
  const unsigned* hu = (const unsigned*)(hNb + (size_t)g*H_);
  const float* wr = W_nv + (size_t)tok*H_;
  #pragma unroll 8
  for (int k = 0; k < 128; ++k) {
    unsigned w2 = hu[k];
    z += u2lo(w2)*wr[2*k] + u2hi(w2)*wr[2*k + 1];
  }
  float term = -(z - M - __logf(Ssum) + __logf(gt_all[g]));
  red[bb] = term;
  __syncthreads();
  for (int o = 64; o > 0; o >>= 1) {
    if (bb < o) red[bb] += red[bb + o];
    __syncthreads();
  }
  if (bb == 0) loss_part[tile] = red[0];
}

__global__ __launch_bounds__(64) void k_fin(const float* lp, float* out) {
  int t = threadIdx.x;
  float v = (t < 29) ? lp[t] : 0.f;
  for (int o = 1; o < 64; o <<= 1) v += __shfl_xor(v, o);
  if (t == 0) out[0] = v;
}

// ---------------------------------------------------------------- launch
extern "C" void kernel_launch(void* const* d_in, const int* in_sizes, int n_in,
                              void* d_out, int out_size, void* d_ws, size_t ws_size,
                              hipStream_t stream) {
  const int* sentence  = (const int*)d_in[0];
  const int* keywords  = (const int*)d_in[1];
  const int* categories= (const int*)d_in[2];
  const int* memsz     = (const int*)d_in[3];
  const float* emb  = (const float*)d_in[5];
  const float* W_ct = (const float*)d_in[6];
  const float* b_ct = (const float*)d_in[7];
  const float* W_ih = (const float*)d_in[8];
  const float* W_hh = (const float*)d_in[9];
  const float* b_ih = (const float*)d_in[10];
  const float* b_hh = (const float*)d_in[11];
  const float* W_n  = (const float*)d_in[12];
  const float* W_k  = (const float*)d_in[13];
  const float* W_v  = (const float*)d_in[14];
  const float* W_nv = (const float*)d_in[15];
  const float* b_nv = (const float*)d_in[16];
  const float* W_g  = (const float*)d_in[17];
  const float* b_g  = (const float*)d_in[18];
  const float* W_hn = (const float*)d_in[19];
  const float* b_hn = (const float*)d_in[20];
  const float* W_hk = (const float*)d_in[21];
  const float* b_hk = (const float*)d_in[22];
  const float* W_hv = (const float*)d_in[23];
  const float* b_hv = (const float*)d_in[24];
  const float* W_mk = (const float*)d_in[25];
  const float* b_mk = (const float*)d_in[26];
  const float* W_mv = (const float*)d_in[27];
  const float* b_mv = (const float*)d_in[28];
  float* out = (float*)d_out;

  char* w = (char*)d_ws;
  size_t off = 0;
  auto alloc = [&](size_t bytes) -> void* {
    void* pp = w + off;
    off = (off + bytes + 255) & ~(size_t)255;
    return pp;
  };
  unsigned* WctTp  = (unsigned*)alloc((size_t)1280*128*4);
  unsigned* WihhTp = (unsigned*)alloc((size_t)512*512*4);
  unsigned* WnkvTp = (unsigned*)alloc((size_t)256*384*4);
  bf16* Whb  = (bf16*)alloc((size_t)90*7936*2);
  bf16* Wmb  = (bf16*)alloc((size_t)20*1024*2);
  bf16* Wnvb = (bf16*)alloc((size_t)VN_*H_*2);
  bf16* hNb  = (bf16*)alloc((size_t)29*B_*H_*2);
  float* gt_all    = (float*)alloc((size_t)29*B_*4);
  float2* pmps     = (float2*)alloc((size_t)29*B_*VCH*8);
  float* loss_part = (float*)alloc(29*4);

  k_prep<<<1024, 256, 0, stream>>>(W_ct, W_ih, W_hh, W_n, W_k, W_v, W_nv,
      W_hn, W_hk, W_hv, W_mk, W_mv, WctTp, WihhTp, WnkvTp, Whb, Wmb, Wnvb);

  LoopP P;
  P.sentence = sentence; P.keywords = keywords; P.categories = categories; P.memsz = memsz;
  P.emb = emb;
  P.WctTp = WctTp; P.WihhTp = WihhTp; P.WnkvTp = WnkvTp;
  P.Whb = Whb; P.Wmb = Wmb;
  P.b_ct = b_ct; P.b_ih = b_ih; P.b_hh = b_hh;
  P.b_hn = b_hn; P.b_hk = b_hk; P.b_hv = b_hv;
  P.b_mk = b_mk; P.b_mv = b_mv; P.W_g = W_g; P.b_g = b_g;
  P.hNb = hNb; P.gt_all = gt_all; P.outg = out + 1;

  k_loop<<<B_, 512, 130944, stream>>>(P);
  k_vocab<<<29*VCH, 256, 131072, stream>>>(hNb, Wnvb, b_nv, pmps);
  k_combine<<<29, 128, 0, stream>>>(pmps, hNb, W_nv, b_nv, gt_all, sentence, loss_part);
  k_fin<<<1, 64, 0, stream>>>(loss_part, out);
}